// Round 9
// baseline (115.160 us; speedup 1.0000x reference)
//
#include <hip/hip_runtime.h>

#define NSEED 256

typedef float v2f __attribute__((ext_vector_type(2)));
typedef float v4f __attribute__((ext_vector_type(4)));

__device__ __forceinline__ float fast_exp(float x) {
  return __builtin_amdgcn_exp2f(x * 1.4426950408889634f);  // e^x via v_exp_f32
}
__device__ __forceinline__ float sigf(float x) {
  return 1.0f / (1.0f + fast_exp(-x));
}
__device__ __forceinline__ float med3(float x, float lo, float hi) {
  // == min(max(x,lo),hi) when lo<=hi (always true for our sorted slots)
  return __builtin_amdgcn_fmed3f(x, lo, hi);
}
__device__ __forceinline__ v2f vfma(v2f a, v2f b, v2f c) {
  return __builtin_elementwise_fma(a, b, c);  // -> v_pk_fma_f32
}

// One-time setup: pair-transposed param table in global ws.
// Per seed-pair p (seeds 2p, 2p+1), 16 floats:
//  {sx_a,sx_b, sy_a,sy_b, a11_a,a11_b, a12_a,a12_b,
//   a21_a,a21_b, a22_a,a22_b, h_a,h_b, g_a,g_b}
__global__ void seed_setup_kernel(const float* __restrict__ seeds,
                                  const float* __restrict__ h_raw,
                                  const float* __restrict__ theta,
                                  const float* __restrict__ a_raw,
                                  const float* __restrict__ seed_gates,
                                  float* __restrict__ Pg) {
  int s = threadIdx.x;
  if (s >= NSEED) return;
  float sx = seeds[2 * s], sy = seeds[2 * s + 1];
  float th = theta[s];
  float c = cosf(th), sn = sinf(th);
  float sc = expf(a_raw[s]);
  float inv = 1.0f / sc;
  float h = 0.5f + 1.5f * sigf(h_raw[s]);  // H_MIN + (H_MAX-H_MIN)*sigmoid
  float g = sigf(seed_gates[s]);
  float* base = Pg + (s >> 1) * 16;
  int b = s & 1;
  base[0 + b] = sx;
  base[2 + b] = sy;
  base[4 + b] = c * inv;
  base[6 + b] = sn * inv;
  base[8 + b] = -sn * sc;
  base[10 + b] = c * sc;
  base[12 + b] = h;
  base[14 + b] = g;
}

// Wave-split: block = 4 waves covering 128 queries. Waves (0,1) own queries
// [base..base+63] with seed halves (0,1); waves (2,3) own [base+64..+127].
// Param address is wave-uniform (readfirstlane) -> s_load path preserved.
__global__ __launch_bounds__(256, 8) void voronoi_kernel(
    const float* __restrict__ uv, const float* __restrict__ seeds,
    const float* __restrict__ w_raw, const float* __restrict__ Pg,
    float* __restrict__ out, int nq) {
  // [grp][field][lane]; fields 0-7 dk(d^2), 8-9 idx, 10-13 sums. 7168 B.
  __shared__ float LD[2][14][64];

  const int wid = threadIdx.x >> 6;
  const int lane = threadIdx.x & 63;
  const int grp = wid >> 1;
  const int half = wid & 1;
  const int shalf = __builtin_amdgcn_readfirstlane(half);
  const int q = blockIdx.x * 128 + grp * 64 + lane;
  const int qc = q < nq ? q : nq - 1;  // clamp: all threads reach syncthreads
  const float2 uvq = ((const float2*)uv)[qc];
  const v2f uu = {uvq.x, uvq.x}, vv = {uvq.y, uvq.y};
  const v2f eps2 = {1e-8f, 1e-8f};
  const float NK = -72.13475204444817f;  // -log2(e)/BETA, BETA=0.02

  float dk0 = 3e38f, dk1 = 3e38f, dk2 = 3e38f, dk3 = 3e38f;
  float dk4 = 3e38f, dk5 = 3e38f, dk6 = 3e38f, dk7 = 3e38f;
  int i0 = 0, i1 = 0;  // half-local; shalf<<7 added after the loop
  v2f S1 = {0.f, 0.f}, S2 = {0.f, 0.f}, Sh = {0.f, 0.f}, Sg = {0.f, 0.f};

  // Exact d^2 comparisons (strict <, old dk0/dk1) reproduce top_k's
  // lowest-index tie-break (round-4 lesson: no key masking).
#define INS(x, sidx)             \
  {                              \
    float _d = (x);              \
    bool c0 = _d < dk0;          \
    bool c1 = _d < dk1;          \
    int sh = c0 ? i0 : (sidx);   \
    i1 = c1 ? sh : i1;           \
    i0 = c0 ? (sidx) : i0;       \
    dk7 = med3(_d, dk6, dk7);    \
    dk6 = med3(_d, dk5, dk6);    \
    dk5 = med3(_d, dk4, dk5);    \
    dk4 = med3(_d, dk3, dk4);    \
    dk3 = med3(_d, dk2, dk3);    \
    dk2 = med3(_d, dk1, dk2);    \
    dk1 = med3(_d, dk0, dk1);    \
    dk0 = fminf(_d, dk0);        \
  }

  // Wave-uniform param base -> scalar s_load (no VALU, no LDS in loop).
  const v4f* __restrict__ PG = (const v4f*)(Pg + shalf * 1024);
#pragma unroll 8
  for (int k = 0; k < 64; ++k) {
    v4f q0 = PG[4 * k + 0];
    v4f q1 = PG[4 * k + 1];
    v4f q2 = PG[4 * k + 2];
    v4f q3 = PG[4 * k + 3];
    v2f dx = uu - q0.xy, dy = vv - q0.zw;
    v2f xp = vfma(q1.xy, dx, q1.zw * dy);
    v2f yp = vfma(q2.xy, dx, q2.zw * dy);
    v2f d2 = vfma(xp, xp, vfma(yp, yp, eps2));
    INS(d2.x, 2 * k);
    INS(d2.y, 2 * k + 1);
    // unshifted softmax terms 2^(-K*d): all consumers are scale-invariant
    float da = __builtin_amdgcn_sqrtf(d2.x);
    float db = __builtin_amdgcn_sqrtf(d2.y);
    v2f e;
    e.x = __builtin_amdgcn_exp2f(da * NK);
    e.y = __builtin_amdgcn_exp2f(db * NK);
    S1 += e;
    S2 = vfma(e, e, S2);
    Sh = vfma(e, q3.xy, Sh);
    Sg = vfma(e, q3.zw, Sg);
  }
#undef INS

  i0 |= shalf << 7;  // globalize seed indices
  i1 |= shalf << 7;

  float S1s = S1.x + S1.y;
  float S2s = S2.x + S2.y;
  float Shs = Sh.x + Sh.y;
  float Sgs = Sg.x + Sg.y;

  if (half == 1) {  // odd wave publishes its partials
    LD[grp][0][lane] = dk0;
    LD[grp][1][lane] = dk1;
    LD[grp][2][lane] = dk2;
    LD[grp][3][lane] = dk3;
    LD[grp][4][lane] = dk4;
    LD[grp][5][lane] = dk5;
    LD[grp][6][lane] = dk6;
    LD[grp][7][lane] = dk7;
    LD[grp][8][lane] = __int_as_float(i0);
    LD[grp][9][lane] = __int_as_float(i1);
    LD[grp][10][lane] = S1s;
    LD[grp][11][lane] = S2s;
    LD[grp][12][lane] = Shs;
    LD[grp][13][lane] = Sgs;
  }
  __syncthreads();
  if (half == 1 || q >= nq) return;

  // ---- merge partner (seeds 128..255) into self (seeds 0..127) ----
  float b0 = LD[grp][0][lane], b1 = LD[grp][1][lane];
  float b2 = LD[grp][2][lane], b3 = LD[grp][3][lane];
  float b4 = LD[grp][4][lane], b5 = LD[grp][5][lane];
  float b6 = LD[grp][6][lane], b7 = LD[grp][7][lane];
  int j0 = __float_as_int(LD[grp][8][lane]);
  int j1 = __float_as_int(LD[grp][9][lane]);
  S1s += LD[grp][10][lane];
  S2s += LD[grp][11][lane];
  Shs += LD[grp][12][lane];
  Sgs += LD[grp][13][lane];

  // top-2 index merge: self = lower seed range, strict < prefers self on
  // ties = top_k lowest-index rule (same logic as r5/r6, which passed).
  bool aw = b0 < dk0;  // partner strictly nearer
  float ec1 = aw ? dk0 : dk1;
  int ic1 = aw ? i0 : i1;
  float ec2 = aw ? b1 : b0;
  int ic2 = aw ? j1 : j0;
  const int I0 = aw ? j0 : i0;
  const int I1 = (ec2 < ec1) ? ic2 : ic1;

  // bitonic half-cleaner + 3-stage clean: lowest 8 of 16
  float m0 = fminf(dk0, b7), m1 = fminf(dk1, b6);
  float m2 = fminf(dk2, b5), m3 = fminf(dk3, b4);
  float m4 = fminf(dk4, b3), m5 = fminf(dk5, b2);
  float m6 = fminf(dk6, b1), m7 = fminf(dk7, b0);
#define CE(a, b)             \
  {                          \
    float _lo = fminf(a, b); \
    float _hi = fmaxf(a, b); \
    a = _lo;                 \
    b = _hi;                 \
  }
  CE(m0, m4) CE(m1, m5) CE(m2, m6) CE(m3, m7)
  CE(m0, m2) CE(m1, m3) CE(m4, m6) CE(m5, m7)
  CE(m0, m1) CE(m2, m3) CE(m4, m5) CE(m6, m7)
#undef CE

  dk0 = __builtin_amdgcn_sqrtf(m0);
  dk1 = __builtin_amdgcn_sqrtf(m1);
  dk2 = __builtin_amdgcn_sqrtf(m2);
  dk3 = __builtin_amdgcn_sqrtf(m3);
  dk4 = __builtin_amdgcn_sqrtf(m4);
  dk5 = __builtin_amdgcn_sqrtf(m5);
  dk6 = __builtin_amdgcn_sqrtf(m6);
  dk7 = __builtin_amdgcn_sqrtf(m7);
  const float d1 = dk0, d3 = dk2;

  // ---- Epilogue ----
  float ax = seeds[2 * I0], ay = seeds[2 * I0 + 1];
  float bx = seeds[2 * I1], by = seeds[2 * I1 + 1];
  float pdx = ax - bx, pdy = ay - by;
  float pd = __builtin_amdgcn_sqrtf(fmaf(pdx, pdx, pdy * pdy));
  float wmax = fmaxf(0.8f * pd, 0.005f + 1e-8f);
  float wr01 = w_raw[(I0 << 8) + I1];
  float wr10 = w_raw[(I1 << 8) + I0];
  float w_pair = 0.005f + (wmax - 0.005f) * 0.5f * (sigf(wr01 * 0.2f) + sigf(wr10 * 0.2f));

  // k_eff = 1/(sum p^2 + EPS) = S1^2/(S2 + EPS*S1^2)  (shift-invariant)
  float s1sq = S1s * S1s;
  float keff = s1sq / fmaf(1e-8f, s1sq, S2s);
  float bonus = 0.15f * sigf((keff - 3.0f) * (1.0f / 0.35f));

  float tt = (d3 - d1) / (w_pair + 1e-8f);
  float t15 = tt * __builtin_amdgcn_sqrtf(tt);
  float triple = 0.15f * fast_exp(-t15);

  float w_eff = w_pair * (1.0f + bonus + triple);

  const float HT = 360.6737602222409f;  // 0.5/tau * log2(e), tau=0.002
  float acc = 1.0f;
  acc += __builtin_amdgcn_exp2f((dk1 - dk2) * HT);
  acc += __builtin_amdgcn_exp2f((dk1 - dk3) * HT);
  acc += __builtin_amdgcn_exp2f((dk1 - dk4) * HT);
  acc += __builtin_amdgcn_exp2f((dk1 - dk5) * HT);
  acc += __builtin_amdgcn_exp2f((dk1 - dk6) * HT);
  acc += __builtin_amdgcn_exp2f((dk1 - dk7) * HT);
  float b1s = 0.5f * (dk1 - d1);
  float sdist = b1s - 0.002f * 0.6931471805599453f * __builtin_amdgcn_logf(acc);

  float wall = sigf((0.5f * w_eff - sdist) * 50.0f);
  float invS1 = 1.0f / S1s;
  out[q] = wall * (Sgs * invS1) * (Shs * invS1);
}

extern "C" void kernel_launch(void* const* d_in, const int* in_sizes, int n_in,
                              void* d_out, int out_size, void* d_ws, size_t ws_size,
                              hipStream_t stream) {
  (void)in_sizes;
  (void)n_in;
  (void)ws_size;
  const float* uv = (const float*)d_in[0];
  const float* seeds = (const float*)d_in[1];
  const float* w_raw = (const float*)d_in[2];
  const float* h_raw = (const float*)d_in[3];
  const float* theta = (const float*)d_in[4];
  const float* a_raw = (const float*)d_in[5];
  const float* gates = (const float*)d_in[6];
  float* out = (float*)d_out;
  float* Pg = (float*)d_ws;  // 128 pairs * 16 floats = 8 KB

  seed_setup_kernel<<<1, 256, 0, stream>>>(seeds, h_raw, theta, a_raw, gates, Pg);
  int nq = out_size;
  long long threads = 2LL * nq;  // 2 waves per 64 queries
  int grid = (int)((threads + 255) / 256);
  voronoi_kernel<<<grid, 256, 0, stream>>>(uv, seeds, w_raw, Pg, out, nq);
}